// Round 14
// baseline (4785.081 us; speedup 1.0000x reference)
//
#include <hip/hip_runtime.h>
#include <hip/hip_fp16.h>

namespace {

constexpr int kS = 1024;   // SEQ
constexpr int kI = 64;     // INPUT_SIZE
constexpr int kH = 128;    // HIDDEN

// fp16 weight layout in d_ws (element offsets)
constexpr int oWx1 = 0;            // [512][64]
constexpr int oWh1 = 32768;        // [512][128]
constexpr int oWx2 = 98304;        // [512][128]
constexpr int oWh2 = 163840;       // [512][128]
constexpr int nW   = 229376;

typedef _Float16 f16x8 __attribute__((ext_vector_type(8)));
typedef float    f32x4 __attribute__((ext_vector_type(4)));

#define MFMA16(a, b, c) __builtin_amdgcn_mfma_f32_16x16x32_f16((a), (b), (c), 0, 0, 0)

__device__ __forceinline__ float rcpf(float x) {
#if __has_builtin(__builtin_amdgcn_rcpf)
  return __builtin_amdgcn_rcpf(x);
#else
  return 1.0f / x;
#endif
}
__device__ __forceinline__ float sigf(float x)  { return rcpf(1.0f + __expf(-x)); }
__device__ __forceinline__ float tanhff(float x){ return 1.0f - 2.0f * rcpf(1.0f + __expf(2.0f * x)); }

__device__ __forceinline__ unsigned packf2(float lo, float hi) {
  _Float16 a = (_Float16)lo, b = (_Float16)hi;
  unsigned short ua = __builtin_bit_cast(unsigned short, a);
  unsigned short ub = __builtin_bit_cast(unsigned short, b);
  return (unsigned)ua | ((unsigned)ub << 16);
}

__device__ __forceinline__ f16x8 ld16(const _Float16* p) {
  return *reinterpret_cast<const f16x8*>(p);
}

// ---- one-shot fp32 -> fp16 weight conversion into d_ws ----
__global__ void cvt_weights(const float* __restrict__ Wx1,
                            const float* __restrict__ Wh1,
                            const float* __restrict__ Wx2,
                            const float* __restrict__ Wh2,
                            _Float16* __restrict__ W16) {
  const int P1 = oWh1 / 2, P2 = oWx2 / 2, P3 = oWh2 / 2, PE = nW / 2;
  for (int i = blockIdx.x * blockDim.x + threadIdx.x; i < PE;
       i += gridDim.x * blockDim.x) {
    const float* s; int e;
    if (i < P1)      { s = Wx1; e = i * 2; }
    else if (i < P2) { s = Wh1; e = (i - P1) * 2; }
    else if (i < P3) { s = Wx2; e = (i - P2) * 2; }
    else             { s = Wh2; e = (i - P3) * 2; }
    const float2 v = *reinterpret_cast<const float2*>(s + e);
    *reinterpret_cast<unsigned*>(W16 + (size_t)i * 2) = packf2(v.x, v.y);
  }
}

// Fused 2-layer LSTM, layer-pipelined by one 8-step tile.
// 256 blocks x 512 thr (8 waves, VGPR cap 128), chains b0,b0+1.
// Waves 0-3: layer 1; waves 4-7: layer 2 (lagging one tile).
// Each wave owns 8 M-tiles (rows [128*lw, 128*lw+128)); Wh kt{0,1} resident
// (16 frags = 64 VGPR), kt{2,3} + all Wx frags streamed from fp16 d_ws.
// A/B share k-chunk packing (HW k-permutation cancels); C/D mapping
// (col=lane&15, row=4*(lane>>4)+reg) is the only load-bearing layout.
__global__ __launch_bounds__(512) void lstm_fused(
    const float* __restrict__ x, const _Float16* __restrict__ W16,
    const float* __restrict__ bx1, const float* __restrict__ bh1,
    const float* __restrict__ bx2, const float* __restrict__ bh2,
    const float* __restrict__ Wc,  const float* __restrict__ bc,
    float* __restrict__ out)
{
  const int tid  = threadIdx.x;
  const int b0   = blockIdx.x * 2;
  const int w    = tid >> 6;
  const int lane = tid & 63;
  const int q    = lane >> 4;
  const int n    = lane & 15;
  const bool isL2 = (w >= 4);
  const int lw   = w & 3;
  const int csel = (n < 2) ? n : 0;

  __shared__ __align__(16) _Float16 xF[8][17][8];       // [kc][col][e] 2.1 KiB
  __shared__ __align__(16) _Float16 h1R[2][16][17][8];  // [buf][kc][col][e] 8.5 KiB
  __shared__ __align__(16) _Float16 h2B[2][2][16][8];   // [par][c][kc][e] 1 KiB
  __shared__ float xg1[16][516];                        // 33 KiB
  __shared__ float xg2[16][516];                        // 33 KiB
  __shared__ float g1[2][512];                          // 4 KiB
  __shared__ float g2[2][512];                          // 4 KiB
  __shared__ float hfin[2][128];                        // 1 KiB

  const _Float16* Wh = W16 + (isL2 ? oWh2 : oWh1);
  const _Float16* Wx = W16 + (isL2 ? oWx2 : oWx1);
  const int ldx = isL2 ? kH : kI;

  // resident Wh kt{0,1} for this wave's 8 M-tiles
  f16x8 Ah0[8], Ah1[8];
#pragma unroll
  for (int i = 0; i < 8; ++i) {
    const int row = (lw * 8 + i) * 16 + n;
    Ah0[i] = ld16(Wh + (size_t)row * kH + q * 8);
    Ah1[i] = ld16(Wh + (size_t)row * kH + 32 + q * 8);
  }

  float bI = 0.f, bF = 0.f, bG = 0.f, bO = 0.f, cst = 0.f;
  const int aj = tid & 127;           // activation cell
  const int ac = (tid >> 7) & 1;      // activation chain
  if (tid < 256) {
    bI = bx1[aj] + bh1[aj];           bF = bx1[aj + 128] + bh1[aj + 128];
    bG = bx1[aj + 256] + bh1[aj + 256]; bO = bx1[aj + 384] + bh1[aj + 384];
  } else {
    bI = bx2[aj] + bh2[aj];           bF = bx2[aj + 128] + bh2[aj + 128];
    bG = bx2[aj + 256] + bh2[aj + 256]; bO = bx2[aj + 384] + bh2[aj + 384];
  }

  // zero h1(-1) (whole h1R buffer 1) and h2(-1) (h2B parity 1)
  for (int i = tid; i < 16 * 17 * 8; i += 512)
    (&h1R[1][0][0][0])[i] = (_Float16)0.f;
  if (tid < 256) {
    (&h2B[1][0][0][0])[tid]       = (_Float16)0.f;
    (&h2B[1][0][0][0])[tid + 256] = (_Float16)0.f;
  }

  for (int T = 0; T <= 128; ++T) {
    const bool hasL1 = (T < 128);
    const bool hasL2 = (T > 0);

    if (hasL1) {   // stage x tile T (512 float2 loads, coalesced)
      const int col = tid >> 5, k2 = (tid & 31) * 2;
      const int c = col & 1, dt = col >> 1;
      const float2 v = *reinterpret_cast<const float2*>(
          x + ((size_t)(b0 + c) * kS + (size_t)(T * 8 + dt)) * kI + k2);
      *reinterpret_cast<unsigned*>(&xF[k2 >> 3][col][k2 & 7]) = packf2(v.x, v.y);
    }
    __syncthreads();   // xF ready; h1R tile T-1 complete

    // ---- batched GEMM phase (all 16 B-cols real) ----
    if (!isL2 && hasL1) {            // xg1 = Wx1 . x(T), K=64
      const char* xb = reinterpret_cast<const char*>(&xF[0][0][0]);
      const f16x8 bf0 = *reinterpret_cast<const f16x8*>(xb + ((q * 17 + n) << 4));
      const f16x8 bf1 = *reinterpret_cast<const f16x8*>(xb + (((4 + q) * 17 + n) << 4));
#pragma unroll
      for (int i = 0; i < 8; ++i) {
        const int row = (lw * 8 + i) * 16 + n;
        const f16x8 w0 = ld16(Wx + (size_t)row * ldx + q * 8);
        const f16x8 w1 = ld16(Wx + (size_t)row * ldx + 32 + q * 8);
        f32x4 e = {0.f, 0.f, 0.f, 0.f};
        e = MFMA16(w0, bf0, e);
        e = MFMA16(w1, bf1, e);
        *reinterpret_cast<f32x4*>(&xg1[n][(lw * 8 + i) * 16 + q * 4]) = e;
      }
    }
    if (isL2 && hasL2) {             // xg2 = Wx2 . h1(tile T-1), K=128
      const char* hb = reinterpret_cast<const char*>(&h1R[(T + 1) & 1][0][0][0]);
      const f16x8 bf0 = *reinterpret_cast<const f16x8*>(hb + (((0 + q) * 17 + n) << 4));
      const f16x8 bf1 = *reinterpret_cast<const f16x8*>(hb + (((4 + q) * 17 + n) << 4));
      const f16x8 bf2 = *reinterpret_cast<const f16x8*>(hb + (((8 + q) * 17 + n) << 4));
      const f16x8 bf3 = *reinterpret_cast<const f16x8*>(hb + (((12 + q) * 17 + n) << 4));
#pragma unroll
      for (int i = 0; i < 8; ++i) {
        const int row = (lw * 8 + i) * 16 + n;
        const f16x8 w0 = ld16(Wx + (size_t)row * ldx + q * 8);
        const f16x8 w1 = ld16(Wx + (size_t)row * ldx + 32 + q * 8);
        const f16x8 w2 = ld16(Wx + (size_t)row * ldx + 64 + q * 8);
        const f16x8 w3 = ld16(Wx + (size_t)row * ldx + 96 + q * 8);
        f32x4 e = {0.f, 0.f, 0.f, 0.f};
        e = MFMA16(w0, bf0, e);  e = MFMA16(w1, bf1, e);
        e = MFMA16(w2, bf2, e);  e = MFMA16(w3, bf3, e);
        *reinterpret_cast<f32x4*>(&xg2[n][(lw * 8 + i) * 16 + q * 4]) = e;
      }
    }
    __syncthreads();   // xg1/xg2 ready

    // ---- 8 fused super-steps ----
    for (int dt = 0; dt < 8; ++dt) {
      if (!isL2 && hasL1) {          // l1 recurrent: B = h1(t-1)
        const char* hb = (dt == 0)
            ? reinterpret_cast<const char*>(&h1R[(T + 1) & 1][0][14 + csel][0])
            : reinterpret_cast<const char*>(&h1R[T & 1][0][(dt - 1) * 2 + csel][0]);
        const f16x8 bf0 = *reinterpret_cast<const f16x8*>(hb + (0 + q) * 272);
        const f16x8 bf1 = *reinterpret_cast<const f16x8*>(hb + (4 + q) * 272);
        const f16x8 bf2 = *reinterpret_cast<const f16x8*>(hb + (8 + q) * 272);
        const f16x8 bf3 = *reinterpret_cast<const f16x8*>(hb + (12 + q) * 272);
#pragma unroll
        for (int i = 0; i < 8; ++i) {
          const int row = (lw * 8 + i) * 16 + n;
          const f16x8 w2 = ld16(Wh + (size_t)row * kH + 64 + q * 8);
          const f16x8 w3 = ld16(Wh + (size_t)row * kH + 96 + q * 8);
          f32x4 d = {0.f, 0.f, 0.f, 0.f};
          d = MFMA16(Ah0[i], bf0, d);  d = MFMA16(Ah1[i], bf1, d);
          d = MFMA16(w2, bf2, d);      d = MFMA16(w3, bf3, d);
          if (n < 2)
            *reinterpret_cast<f32x4*>(&g1[n][(lw * 8 + i) * 16 + q * 4]) = d;
        }
      }
      if (isL2 && hasL2) {           // l2 recurrent: B = h2(t2-1)
        const int t2 = (T - 1) * 8 + dt;
        const char* hb = reinterpret_cast<const char*>(&h2B[(t2 + 1) & 1][csel][0][0]);
        const f16x8 bf0 = *reinterpret_cast<const f16x8*>(hb + ((0 + q) << 4));
        const f16x8 bf1 = *reinterpret_cast<const f16x8*>(hb + ((4 + q) << 4));
        const f16x8 bf2 = *reinterpret_cast<const f16x8*>(hb + ((8 + q) << 4));
        const f16x8 bf3 = *reinterpret_cast<const f16x8*>(hb + ((12 + q) << 4));
#pragma unroll
        for (int i = 0; i < 8; ++i) {
          const int row = (lw * 8 + i) * 16 + n;
          const f16x8 w2 = ld16(Wh + (size_t)row * kH + 64 + q * 8);
          const f16x8 w3 = ld16(Wh + (size_t)row * kH + 96 + q * 8);
          f32x4 d = {0.f, 0.f, 0.f, 0.f};
          d = MFMA16(Ah0[i], bf0, d);  d = MFMA16(Ah1[i], bf1, d);
          d = MFMA16(w2, bf2, d);      d = MFMA16(w3, bf3, d);
          if (n < 2)
            *reinterpret_cast<f32x4*>(&g2[n][(lw * 8 + i) * 16 + q * 4]) = d;
        }
      }
      __syncthreads();

      if (tid < 256 && hasL1) {      // l1 activation
        const int col = dt * 2 + ac;
        const float gi = xg1[col][aj]       + g1[ac][aj]       + bI;
        const float gf = xg1[col][aj + 128] + g1[ac][aj + 128] + bF;
        const float gg = xg1[col][aj + 256] + g1[ac][aj + 256] + bG;
        const float go = xg1[col][aj + 384] + g1[ac][aj + 384] + bO;
        cst = sigf(gf) * cst + sigf(gi) * tanhff(gg);
        h1R[T & 1][aj >> 3][col][aj & 7] = (_Float16)(sigf(go) * tanhff(cst));
      } else if (tid >= 256 && hasL2) {   // l2 activation
        const int t2 = (T - 1) * 8 + dt;
        const int col = dt * 2 + ac;
        const float gi = xg2[col][aj]       + g2[ac][aj]       + bI;
        const float gf = xg2[col][aj + 128] + g2[ac][aj + 128] + bF;
        const float gg = xg2[col][aj + 256] + g2[ac][aj + 256] + bG;
        const float go = xg2[col][aj + 384] + g2[ac][aj + 384] + bO;
        cst = sigf(gf) * cst + sigf(gi) * tanhff(gg);
        const float h = sigf(go) * tanhff(cst);
        h2B[t2 & 1][ac][aj >> 3][aj & 7] = (_Float16)h;
        if (t2 == kS - 1) hfin[ac][aj] = h;
      }
      __syncthreads();
    }
  }

  // classifier head: logits[b0+c, m] = Wc[m,:] . h2fin[c] + bc[m]
  if (tid < 8) {
    const int m = tid & 3, c = tid >> 2;
    const float* wr = Wc + (size_t)m * kH;
    float s0 = 0.f, s1 = 0.f, s2 = 0.f, s3 = 0.f;
#pragma unroll
    for (int j = 0; j < kH; j += 4) {
      s0 = fmaf(wr[j],     hfin[c][j],     s0);
      s1 = fmaf(wr[j + 1], hfin[c][j + 1], s1);
      s2 = fmaf(wr[j + 2], hfin[c][j + 2], s2);
      s3 = fmaf(wr[j + 3], hfin[c][j + 3], s3);
    }
    out[(size_t)(b0 + c) * 4 + m] = bc[m] + ((s0 + s1) + (s2 + s3));
  }
}

} // namespace

extern "C" void kernel_launch(void* const* d_in, const int* in_sizes, int n_in,
                              void* d_out, int out_size, void* d_ws, size_t ws_size,
                              hipStream_t stream) {
  const float* x   = (const float*)d_in[0];
  const float* Wx1 = (const float*)d_in[1];
  const float* bx1 = (const float*)d_in[2];
  const float* Wh1 = (const float*)d_in[3];
  const float* bh1 = (const float*)d_in[4];
  const float* Wx2 = (const float*)d_in[5];
  const float* bx2 = (const float*)d_in[6];
  const float* Wh2 = (const float*)d_in[7];
  const float* bh2 = (const float*)d_in[8];
  const float* Wc  = (const float*)d_in[9];
  const float* bc  = (const float*)d_in[10];

  _Float16* W16 = (_Float16*)d_ws;   // 448 KiB fp16 weights

  hipLaunchKernelGGL(cvt_weights, dim3(448), dim3(256), 0, stream,
                     Wx1, Wh1, Wx2, Wh2, W16);
  hipLaunchKernelGGL(lstm_fused, dim3(256), dim3(512), 0, stream,
                     x, W16, bx1, bh1, bx2, bh2, Wc, bc, (float*)d_out);
}

// Round 15
// 1800.348 us; speedup vs baseline: 2.6579x; 2.6579x over previous
//
#include <hip/hip_runtime.h>
#include <hip/hip_fp16.h>

namespace {

constexpr int kS = 1024;   // SEQ
constexpr int kI = 64;     // INPUT_SIZE
constexpr int kH = 128;    // HIDDEN

// fp16 weight layout in d_ws (element offsets)
constexpr int oWx1 = 0;            // [512][64]
constexpr int oWh1 = 32768;        // [512][128]
constexpr int oWx2 = 98304;        // [512][128]
constexpr int oWh2 = 163840;       // [512][128]
constexpr int nW   = 229376;

typedef _Float16 f16x8 __attribute__((ext_vector_type(8)));
typedef float    f32x4 __attribute__((ext_vector_type(4)));

#define MFMA16(a, b, c) __builtin_amdgcn_mfma_f32_16x16x32_f16((a), (b), (c), 0, 0, 0)

__device__ __forceinline__ float rcpf(float x) {
#if __has_builtin(__builtin_amdgcn_rcpf)
  return __builtin_amdgcn_rcpf(x);
#else
  return 1.0f / x;
#endif
}
__device__ __forceinline__ float sigf(float x)  { return rcpf(1.0f + __expf(-x)); }
__device__ __forceinline__ float tanhff(float x){ return 1.0f - 2.0f * rcpf(1.0f + __expf(2.0f * x)); }

template <int P>
__device__ __forceinline__ void prio() {
#if __has_builtin(__builtin_amdgcn_s_setprio)
  __builtin_amdgcn_s_setprio(P);
#endif
}
__device__ __forceinline__ void schedbar() {
#if __has_builtin(__builtin_amdgcn_sched_barrier)
  __builtin_amdgcn_sched_barrier(0);
#endif
}

__device__ __forceinline__ unsigned packf2(float lo, float hi) {
  _Float16 a = (_Float16)lo, b = (_Float16)hi;
  unsigned short ua = __builtin_bit_cast(unsigned short, a);
  unsigned short ub = __builtin_bit_cast(unsigned short, b);
  return (unsigned)ua | ((unsigned)ub << 16);
}

__device__ __forceinline__ f16x8 ld16(const _Float16* p) {
  return *reinterpret_cast<const f16x8*>(p);
}

// ---- one-shot fp32 -> fp16 weight conversion into d_ws ----
__global__ void cvt_weights(const float* __restrict__ Wx1,
                            const float* __restrict__ Wh1,
                            const float* __restrict__ Wx2,
                            const float* __restrict__ Wh2,
                            _Float16* __restrict__ W16) {
  const int P1 = oWh1 / 2, P2 = oWx2 / 2, P3 = oWh2 / 2, PE = nW / 2;
  for (int i = blockIdx.x * blockDim.x + threadIdx.x; i < PE;
       i += gridDim.x * blockDim.x) {
    const float* s; int e;
    if (i < P1)      { s = Wx1; e = i * 2; }
    else if (i < P2) { s = Wh1; e = (i - P1) * 2; }
    else if (i < P3) { s = Wx2; e = (i - P2) * 2; }
    else             { s = Wh2; e = (i - P3) * 2; }
    const float2 v = *reinterpret_cast<const float2*>(s + e);
    *reinterpret_cast<unsigned*>(W16 + (size_t)i * 2) = packf2(v.x, v.y);
  }
}

// Fused 2-layer LSTM, layer-pipelined by one 8-step tile.
// 256 blocks x 1024 thr (16 waves). launch_bounds(1024,1): 1 block x 16 waves
// = 4 waves/SIMD -> VGPR cap 128 (the (512,2)->128 / (512,4)->64 ledger).
// Waves 0-7: layer 1; waves 8-15: layer 2 (lagging one tile). Each wave owns
// 4 M-tiles with Wh FULLY resident (16 frags = 64 VGPR). Wx is streamed from
// fp16 d_ws only in the per-tile GEMM phase (latency amortized over 8 steps);
// the per-step recurrent loop touches ONLY registers + broadcast LDS reads.
// A/B share k-chunk packing (HW k-permutation cancels); C/D mapping
// (col=lane&15, row=4*(lane>>4)+reg) is the only load-bearing layout.
__global__ __launch_bounds__(1024, 1) void lstm_fused(
    const float* __restrict__ x, const _Float16* __restrict__ W16,
    const float* __restrict__ bx1, const float* __restrict__ bh1,
    const float* __restrict__ bx2, const float* __restrict__ bh2,
    const float* __restrict__ Wc,  const float* __restrict__ bc,
    float* __restrict__ out)
{
  const int tid  = threadIdx.x;
  const int b0   = blockIdx.x * 2;
  const int w    = tid >> 6;
  const int lane = tid & 63;
  const int q    = lane >> 4;
  const int n    = lane & 15;
  const bool isL2 = (w >= 8);
  const int lw   = w & 7;
  const int csel = (n < 2) ? n : 0;

  __shared__ __align__(16) _Float16 xF[8][17][8];       // [kc][col][e] 2.1 KiB
  __shared__ __align__(16) _Float16 h1R[2][16][17][8];  // [buf][kc][col][e] 8.5 KiB
  __shared__ __align__(16) _Float16 h2B[2][2][16][8];   // [par][c][kc][e] 1 KiB
  __shared__ float xg1[16][516];                        // 33 KiB
  __shared__ float xg2[16][516];                        // 33 KiB
  __shared__ float g1[2][512];                          // 4 KiB
  __shared__ float g2[2][512];                          // 4 KiB
  __shared__ float hfin[2][128];                        // 1 KiB

  const _Float16* Wh = W16 + (isL2 ? oWh2 : oWh1);
  const _Float16* Wx = W16 + (isL2 ? oWx2 : oWx1);
  const int ldx = isL2 ? kH : kI;

  // fully resident Wh for this wave's 4 M-tiles: 16 frags = 64 VGPR
  f16x8 Ah[4][4];
#pragma unroll
  for (int i = 0; i < 4; ++i) {
    const int row = (lw * 4 + i) * 16 + n;
#pragma unroll
    for (int kt = 0; kt < 4; ++kt)
      Ah[i][kt] = ld16(Wh + (size_t)row * kH + kt * 32 + q * 8);
  }

  float bI = 0.f, bF = 0.f, bG = 0.f, bO = 0.f, cst = 0.f;
  const int aj = tid & 127;
  const int ac = (tid >> 7) & 1;
  if (tid < 256) {
    bI = bx1[aj] + bh1[aj];             bF = bx1[aj + 128] + bh1[aj + 128];
    bG = bx1[aj + 256] + bh1[aj + 256]; bO = bx1[aj + 384] + bh1[aj + 384];
  } else if (tid >= 512 && tid < 768) {
    bI = bx2[aj] + bh2[aj];             bF = bx2[aj + 128] + bh2[aj + 128];
    bG = bx2[aj + 256] + bh2[aj + 256]; bO = bx2[aj + 384] + bh2[aj + 384];
  }

  // zero h1(-1) (whole h1R buffer 1) and h2(-1) (h2B parity 1)
  for (int i = tid; i < 16 * 17 * 8; i += 1024)
    (&h1R[1][0][0][0])[i] = (_Float16)0.f;
  if (tid < 512) (&h2B[1][0][0][0])[tid] = (_Float16)0.f;

  for (int T = 0; T <= 128; ++T) {
    const bool hasL1 = (T < 128);
    const bool hasL2 = (T > 0);

    if (hasL1 && tid < 512) {   // stage x tile T (512 float2 loads, coalesced)
      const int col = tid >> 5, k2 = (tid & 31) * 2;
      const int c = col & 1, dt = col >> 1;
      const float2 v = *reinterpret_cast<const float2*>(
          x + ((size_t)(b0 + c) * kS + (size_t)(T * 8 + dt)) * kI + k2);
      *reinterpret_cast<unsigned*>(&xF[k2 >> 3][col][k2 & 7]) = packf2(v.x, v.y);
    }
    __syncthreads();   // xF ready; h1R tile T-1 complete

    // ---- batched GEMM phase (Wx streamed; all 16 B-cols real) ----
    if (!isL2 && hasL1) {            // xg1 = Wx1 . x(T), K=64
      const char* xb = reinterpret_cast<const char*>(&xF[0][0][0]);
      const f16x8 bf0 = *reinterpret_cast<const f16x8*>(xb + ((q * 17 + n) << 4));
      const f16x8 bf1 = *reinterpret_cast<const f16x8*>(xb + (((4 + q) * 17 + n) << 4));
#pragma unroll
      for (int i = 0; i < 4; ++i) {
        const int row = (lw * 4 + i) * 16 + n;
        const f16x8 w0 = ld16(Wx + (size_t)row * ldx + q * 8);
        const f16x8 w1 = ld16(Wx + (size_t)row * ldx + 32 + q * 8);
        f32x4 e = {0.f, 0.f, 0.f, 0.f};
        e = MFMA16(w0, bf0, e);
        e = MFMA16(w1, bf1, e);
        *reinterpret_cast<f32x4*>(&xg1[n][(lw * 4 + i) * 16 + q * 4]) = e;
      }
    }
    if (isL2 && hasL2) {             // xg2 = Wx2 . h1(tile T-1), K=128
      const char* hb = reinterpret_cast<const char*>(&h1R[(T + 1) & 1][0][0][0]);
      const f16x8 bf0 = *reinterpret_cast<const f16x8*>(hb + (((0 + q) * 17 + n) << 4));
      const f16x8 bf1 = *reinterpret_cast<const f16x8*>(hb + (((4 + q) * 17 + n) << 4));
      const f16x8 bf2 = *reinterpret_cast<const f16x8*>(hb + (((8 + q) * 17 + n) << 4));
      const f16x8 bf3 = *reinterpret_cast<const f16x8*>(hb + (((12 + q) * 17 + n) << 4));
#pragma unroll
      for (int i = 0; i < 4; ++i) {
        const int row = (lw * 4 + i) * 16 + n;
        f32x4 e = {0.f, 0.f, 0.f, 0.f};
        {
          const f16x8 w0 = ld16(Wx + (size_t)row * ldx + q * 8);
          const f16x8 w1 = ld16(Wx + (size_t)row * ldx + 32 + q * 8);
          e = MFMA16(w0, bf0, e);  e = MFMA16(w1, bf1, e);
        }
        schedbar();   // cap streamed-weight live range (VGPR budget)
        {
          const f16x8 w2 = ld16(Wx + (size_t)row * ldx + 64 + q * 8);
          const f16x8 w3 = ld16(Wx + (size_t)row * ldx + 96 + q * 8);
          e = MFMA16(w2, bf2, e);  e = MFMA16(w3, bf3, e);
        }
        *reinterpret_cast<f32x4*>(&xg2[n][(lw * 4 + i) * 16 + q * 4]) = e;
      }
    }
    __syncthreads();   // xg1/xg2 ready

    // ---- 8 fused super-steps (pure resident MFMA + broadcast LDS reads) ----
    for (int dt = 0; dt < 8; ++dt) {
      if (!isL2 && hasL1) {          // l1 recurrent: B = h1(t-1)
        const char* hb = (dt == 0)
            ? reinterpret_cast<const char*>(&h1R[(T + 1) & 1][0][14 + csel][0])
            : reinterpret_cast<const char*>(&h1R[T & 1][0][(dt - 1) * 2 + csel][0]);
        const f16x8 bf0 = *reinterpret_cast<const f16x8*>(hb + (0 + q) * 272);
        const f16x8 bf1 = *reinterpret_cast<const f16x8*>(hb + (4 + q) * 272);
        const f16x8 bf2 = *reinterpret_cast<const f16x8*>(hb + (8 + q) * 272);
        const f16x8 bf3 = *reinterpret_cast<const f16x8*>(hb + (12 + q) * 272);
        prio<1>();
#pragma unroll
        for (int i = 0; i < 4; ++i) {
          f32x4 d = {0.f, 0.f, 0.f, 0.f};
          d = MFMA16(Ah[i][0], bf0, d);  d = MFMA16(Ah[i][1], bf1, d);
          d = MFMA16(Ah[i][2], bf2, d);  d = MFMA16(Ah[i][3], bf3, d);
          if (n < 2)
            *reinterpret_cast<f32x4*>(&g1[n][(lw * 4 + i) * 16 + q * 4]) = d;
        }
        prio<0>();
      }
      if (isL2 && hasL2) {           // l2 recurrent: B = h2(t2-1)
        const int t2 = (T - 1) * 8 + dt;
        const char* hb = reinterpret_cast<const char*>(&h2B[(t2 + 1) & 1][csel][0][0]);
        const f16x8 bf0 = *reinterpret_cast<const f16x8*>(hb + ((0 + q) << 4));
        const f16x8 bf1 = *reinterpret_cast<const f16x8*>(hb + ((4 + q) << 4));
        const f16x8 bf2 = *reinterpret_cast<const f16x8*>(hb + ((8 + q) << 4));
        const f16x8 bf3 = *reinterpret_cast<const f16x8*>(hb + ((12 + q) << 4));
        prio<1>();
#pragma unroll
        for (int i = 0; i < 4; ++i) {
          f32x4 d = {0.f, 0.f, 0.f, 0.f};
          d = MFMA16(Ah[i][0], bf0, d);  d = MFMA16(Ah[i][1], bf1, d);
          d = MFMA16(Ah[i][2], bf2, d);  d = MFMA16(Ah[i][3], bf3, d);
          if (n < 2)
            *reinterpret_cast<f32x4*>(&g2[n][(lw * 4 + i) * 16 + q * 4]) = d;
        }
        prio<0>();
      }
      __syncthreads();

      if (tid < 256 && hasL1) {      // l1 activation
        const int col = dt * 2 + ac;
        const float gi = xg1[col][aj]       + g1[ac][aj]       + bI;
        const float gf = xg1[col][aj + 128] + g1[ac][aj + 128] + bF;
        const float gg = xg1[col][aj + 256] + g1[ac][aj + 256] + bG;
        const float go = xg1[col][aj + 384] + g1[ac][aj + 384] + bO;
        cst = sigf(gf) * cst + sigf(gi) * tanhff(gg);
        h1R[T & 1][aj >> 3][col][aj & 7] = (_Float16)(sigf(go) * tanhff(cst));
      } else if (tid >= 512 && tid < 768 && hasL2) {   // l2 activation
        const int t2 = (T - 1) * 8 + dt;
        const int col = dt * 2 + ac;
        const float gi = xg2[col][aj]       + g2[ac][aj]       + bI;
        const float gf = xg2[col][aj + 128] + g2[ac][aj + 128] + bF;
        const float gg = xg2[col][aj + 256] + g2[ac][aj + 256] + bG;
        const float go = xg2[col][aj + 384] + g2[ac][aj + 384] + bO;
        cst = sigf(gf) * cst + sigf(gi) * tanhff(gg);
        const float h = sigf(go) * tanhff(cst);
        h2B[t2 & 1][ac][aj >> 3][aj & 7] = (_Float16)h;
        if (t2 == kS - 1) hfin[ac][aj] = h;
      }
      __syncthreads();
    }
  }

  // classifier head: logits[b0+c, m] = Wc[m,:] . h2fin[c] + bc[m]
  if (tid < 8) {
    const int m = tid & 3, c = tid >> 2;
    const float* wr = Wc + (size_t)m * kH;
    float s0 = 0.f, s1 = 0.f, s2 = 0.f, s3 = 0.f;
#pragma unroll
    for (int j = 0; j < kH; j += 4) {
      s0 = fmaf(wr[j],     hfin[c][j],     s0);
      s1 = fmaf(wr[j + 1], hfin[c][j + 1], s1);
      s2 = fmaf(wr[j + 2], hfin[c][j + 2], s2);
      s3 = fmaf(wr[j + 3], hfin[c][j + 3], s3);
    }
    out[(size_t)(b0 + c) * 4 + m] = bc[m] + ((s0 + s1) + (s2 + s3));
  }
}

} // namespace

extern "C" void kernel_launch(void* const* d_in, const int* in_sizes, int n_in,
                              void* d_out, int out_size, void* d_ws, size_t ws_size,
                              hipStream_t stream) {
  const float* x   = (const float*)d_in[0];
  const float* Wx1 = (const float*)d_in[1];
  const float* bx1 = (const float*)d_in[2];
  const float* Wh1 = (const float*)d_in[3];
  const float* bh1 = (const float*)d_in[4];
  const float* Wx2 = (const float*)d_in[5];
  const float* bx2 = (const float*)d_in[6];
  const float* Wh2 = (const float*)d_in[7];
  const float* bh2 = (const float*)d_in[8];
  const float* Wc  = (const float*)d_in[9];
  const float* bc  = (const float*)d_in[10];

  _Float16* W16 = (_Float16*)d_ws;   // 448 KiB fp16 weights

  hipLaunchKernelGGL(cvt_weights, dim3(448), dim3(256), 0, stream,
                     Wx1, Wh1, Wx2, Wh2, W16);
  hipLaunchKernelGGL(lstm_fused, dim3(256), dim3(1024), 0, stream,
                     x, W16, bx1, bh1, bx2, bh2, Wc, bc, (float*)d_out);
}